// Round 1
// 665.782 us; speedup vs baseline: 2.0707x; 2.0707x over previous
//
#include <hip/hip_runtime.h>

// IndRNN, 2 layers. T=2048, B=32, D=H=512, ALL FP32.
//
// Pipeline (in d_out, 128 MiB):
//   split_bf16: w_ih0/w_ih1 -> d_ws as (hi,lo) bf16 pairs   (2 MiB total)
//   gemm_mfma : x -> d_out               (u0)   bf16x3 MFMA emulation
//   scan_inplace on d_out                (h0)
//   gemm_mfma : d_out -> d_out in-place  (u1)
//   scan_inplace on d_out                (y)
//
// bf16x3 emulation: a*b ~= a_hi*b_hi + a_hi*b_lo + a_lo*b_hi with RNE splits.
// Residual (lo*lo + split rounding) <= ~2^-17 relative; over K=512 with
// |x|<~5, |w|<~0.05 worst-case abs error ~5e-4 << 4.26e-3 threshold
// (realistically ~1e-5 with random signs). MFMA products bf16*bf16->fp32
// are exact; accumulation is fp32 like the reference.
//
// In-place safety of gemm_mfma (layer 1, A==C): each block reads ONLY its own
// 64 A rows (panel loads) and writes ONLY those rows, and all C stores happen
// in the epilogue after the final K panel has been consumed. No cross-block
// row sharing exists for this GEMM shape => no staging needed for safety.
//
// MFMA fragment layout (m97-verified convention for mfma_f32_16x16x32_bf16):
//   A/B frag: lane holds 8 contiguous k at row/col = lane&15, k0 = (lane>>4)*8
//   C/D frag: col = lane&15, row = (lane>>4)*4 + reg
//
// LDS: A K-panels only, double buffered, padded stride 40 ushorts
// (80 B row pitch => fragment ds_read_b128 is a free 2-way bank conflict).

#define KK 512
#define NN 512
#define GR 64              // rows per MFMA GEMM block
#define KSTEP 32
#define NSTEPS (KK / KSTEP)   // 16
#define LDA_P 40           // padded ushort row stride for a 32-wide K panel

typedef __attribute__((ext_vector_type(8))) short bf16x8;
typedef __attribute__((ext_vector_type(4))) float f32x4;

__device__ __forceinline__ ushort f2bf_rne(float f) {
    unsigned u = __float_as_uint(f);
    u += 0x7fffu + ((u >> 16) & 1u);
    return (ushort)(u >> 16);
}
__device__ __forceinline__ float bf2f(ushort h) {
    return __uint_as_float(((unsigned)h) << 16);
}

// Split fp32 weights into bf16 hi/lo arrays (RNE both stages).
__global__ __launch_bounds__(256) void split_bf16(
    const float* __restrict__ W, ushort* __restrict__ Bh, ushort* __restrict__ Bl)
{
    const int i = blockIdx.x * blockDim.x + threadIdx.x;   // float4 index
    if (i >= (NN * KK) / 4) return;
    const float4 v = ((const float4*)W)[i];
    ushort4 h, l;
    h.x = f2bf_rne(v.x); l.x = f2bf_rne(v.x - bf2f(h.x));
    h.y = f2bf_rne(v.y); l.y = f2bf_rne(v.y - bf2f(h.y));
    h.z = f2bf_rne(v.z); l.z = f2bf_rne(v.z - bf2f(h.z));
    h.w = f2bf_rne(v.w); l.w = f2bf_rne(v.w - bf2f(h.w));
    ((ushort4*)Bh)[i] = h;
    ((ushort4*)Bl)[i] = l;
}

__device__ __forceinline__ void stage_panel(ushort* dh, ushort* dl, float4 v) {
    ushort4 h, l;
    h.x = f2bf_rne(v.x); l.x = f2bf_rne(v.x - bf2f(h.x));
    h.y = f2bf_rne(v.y); l.y = f2bf_rne(v.y - bf2f(h.y));
    h.z = f2bf_rne(v.z); l.z = f2bf_rne(v.z - bf2f(h.z));
    h.w = f2bf_rne(v.w); l.w = f2bf_rne(v.w - bf2f(h.w));
    *(ushort4*)dh = h;
    *(ushort4*)dl = l;
}

// C[m][n] = bias[n] + sum_k A[m][k] * B[n][k], B pre-split to bf16 hi/lo.
// Block: 512 threads (8 waves), owns rows [blockIdx.x*64, +64), all 512 cols.
// Wave w owns cols [w*64, +64): 4x4 fragments of 16x16. A==C allowed.
__global__ __launch_bounds__(512, 2) void gemm_mfma_f32(
    const float* A,                        // no __restrict__: may alias C
    const ushort* __restrict__ Bh,
    const ushort* __restrict__ Bl,
    const float* __restrict__ bias,
    float* C)
{
    __shared__ __align__(16) ushort As[2][2][GR * LDA_P];  // [buf][hi/lo] 20.5 KiB

    const int tid  = threadIdx.x;
    const int wave = tid >> 6;
    const int lane = tid & 63;
    const int l15  = lane & 15;
    const int l4   = lane >> 4;
    const int r0   = blockIdx.x * GR;

    // Panel loader: thread t -> A[r0 + t/8][ks*32 + (t%8)*4 .. +4]
    const int prow = tid >> 3;
    const int pk4  = (tid & 7) << 2;
    const float* aptr = A + (size_t)(r0 + prow) * KK + pk4;
    const int woff = prow * LDA_P + pk4;

    // B fragment base: col = wave*64 + cf*16 + l15, k-chunk = l4*8
    const int ncol0 = wave * 64 + l15;
    const ushort* bhp = Bh + (size_t)ncol0 * KK + l4 * 8;
    const ushort* blp = Bl + (size_t)ncol0 * KK + l4 * 8;

    f32x4 acc[4][4];
#pragma unroll
    for (int i = 0; i < 4; ++i)
#pragma unroll
        for (int j = 0; j < 4; ++j) acc[i][j] = {0.f, 0.f, 0.f, 0.f};

    // Prologue: load panels 0,1; stage panel 0 into buf 0.
    float4 pf[2];
    pf[0] = *(const float4*)(aptr);
    pf[1] = *(const float4*)(aptr + KSTEP);
    stage_panel(&As[0][0][woff], &As[0][1][woff], pf[0]);
    __syncthreads();

#pragma unroll
    for (int ks = 0; ks < NSTEPS; ++ks) {
        const int cur = ks & 1;
        // Prefetch panel ks+2 into the slot whose panel (ks) is already staged.
        if (ks + 2 < NSTEPS)
            pf[cur] = *(const float4*)(aptr + (size_t)(ks + 2) * KSTEP);

        // Issue B fragment loads (L2-resident) and A fragment LDS reads.
        bf16x8 bh[4], bl[4], ah[4], al[4];
#pragma unroll
        for (int cf = 0; cf < 4; ++cf) {
            bh[cf] = *(const bf16x8*)(bhp + (size_t)cf * 16 * KK + ks * KSTEP);
            bl[cf] = *(const bf16x8*)(blp + (size_t)cf * 16 * KK + ks * KSTEP);
        }
#pragma unroll
        for (int rf = 0; rf < 4; ++rf) {
            const int ao = (rf * 16 + l15) * LDA_P + l4 * 8;
            ah[rf] = *(const bf16x8*)&As[cur][0][ao];
            al[rf] = *(const bf16x8*)&As[cur][1][ao];
        }

        // Stage panel ks+1 into the other buffer (loaded last iteration).
        if (ks + 1 < NSTEPS)
            stage_panel(&As[cur ^ 1][0][woff], &As[cur ^ 1][1][woff], pf[cur ^ 1]);

        // 48 MFMAs: hi*hi + hi*lo + lo*hi accumulated into the same acc.
#pragma unroll
        for (int rf = 0; rf < 4; ++rf)
#pragma unroll
            for (int cf = 0; cf < 4; ++cf) {
                acc[rf][cf] = __builtin_amdgcn_mfma_f32_16x16x32_bf16(
                    al[rf], bh[cf], acc[rf][cf], 0, 0, 0);
                acc[rf][cf] = __builtin_amdgcn_mfma_f32_16x16x32_bf16(
                    ah[rf], bl[cf], acc[rf][cf], 0, 0, 0);
                acc[rf][cf] = __builtin_amdgcn_mfma_f32_16x16x32_bf16(
                    ah[rf], bh[cf], acc[rf][cf], 0, 0, 0);
            }
        __syncthreads();
    }

    // Epilogue: bias add + store. Only our own rows => in-place safe.
#pragma unroll
    for (int cf = 0; cf < 4; ++cf) {
        const int col = ncol0 + cf * 16;
        const float bv = bias[col];
#pragma unroll
        for (int rf = 0; rf < 4; ++rf) {
            float* cp = C + (size_t)(r0 + rf * 16 + l4 * 4) * NN + col;
#pragma unroll
            for (int j = 0; j < 4; ++j)
                cp[(size_t)j * NN] = acc[rf][cf][j] + bv;
        }
    }
}

// ---------- fallback vector GEMM (previous proven kernel) ----------
#define GR_OLD 32
__global__ __launch_bounds__(256) void gemm_rows_f32(
    const float* A, const float* __restrict__ Bw,
    const float* __restrict__ bias, float* C)
{
    __shared__ __align__(16) float Asf[GR_OLD][KK];
    const int r0 = blockIdx.x * GR_OLD;
    {
        const float4* src = (const float4*)(A + (size_t)r0 * KK);
        float4* dst = (float4*)&Asf[0][0];
#pragma unroll
        for (int i = 0; i < (GR_OLD * KK) / (4 * 256); ++i)
            dst[threadIdx.x + i * 256] = src[threadIdx.x + i * 256];
    }
    __syncthreads();
    const int col0 = threadIdx.x * 2;
    const float* b0 = Bw + (size_t)col0 * KK;
    const float* b1 = b0 + KK;
    float acc0[GR_OLD], acc1[GR_OLD];
#pragma unroll
    for (int m = 0; m < GR_OLD; ++m) { acc0[m] = 0.f; acc1[m] = 0.f; }
    for (int k4 = 0; k4 < KK / 4; ++k4) {
        const float4 w0 = *(const float4*)(b0 + k4 * 4);
        const float4 w1 = *(const float4*)(b1 + k4 * 4);
#pragma unroll
        for (int m = 0; m < GR_OLD; ++m) {
            const float4 a = *(const float4*)&Asf[m][k4 * 4];
            acc0[m] = fmaf(a.x, w0.x, acc0[m]);
            acc0[m] = fmaf(a.y, w0.y, acc0[m]);
            acc0[m] = fmaf(a.z, w0.z, acc0[m]);
            acc0[m] = fmaf(a.w, w0.w, acc0[m]);
            acc1[m] = fmaf(a.x, w1.x, acc1[m]);
            acc1[m] = fmaf(a.y, w1.y, acc1[m]);
            acc1[m] = fmaf(a.z, w1.z, acc1[m]);
            acc1[m] = fmaf(a.w, w1.w, acc1[m]);
        }
    }
    const float bv0 = bias[col0];
    const float bv1 = bias[col0 + 1];
#pragma unroll
    for (int m = 0; m < GR_OLD; ++m) {
        float2 o; o.x = acc0[m] + bv0; o.y = acc1[m] + bv1;
        *(float2*)(C + (size_t)(r0 + m) * NN + col0) = o;
    }
}

// In-place chunked recurrence: u[t,e] -> h[t,e]. Unchanged (HBM-roofline-ish).
__global__ __launch_bounds__(256) void scan_inplace_f32(
    float* u, const float* __restrict__ w_hh, int T, int E, int H)
{
    const int e4 = (blockIdx.x * blockDim.x + threadIdx.x) * 4;
    if (e4 >= E) return;
    const int chunk = blockIdx.y;

    const float4 w = *(const float4*)(w_hh + (e4 & (H - 1)));
    float4 h = make_float4(0.f, 0.f, 0.f, 0.f);

    const int t0 = chunk * 64;
    const int tw = (t0 >= 16) ? (t0 - 16) : 0;

    for (int t = tw; t < t0; ++t) {
        const float4 uv = *(const float4*)(u + (size_t)t * E + e4);
        h.x = fmaxf(fmaf(w.x, h.x, uv.x), 0.f);
        h.y = fmaxf(fmaf(w.y, h.y, uv.y), 0.f);
        h.z = fmaxf(fmaf(w.z, h.z, uv.z), 0.f);
        h.w = fmaxf(fmaf(w.w, h.w, uv.w), 0.f);
    }
    for (int t = t0; t < t0 + 64; ++t) {
        float* p = u + (size_t)t * E + e4;
        const float4 uv = *(const float4*)p;
        h.x = fmaxf(fmaf(w.x, h.x, uv.x), 0.f);
        h.y = fmaxf(fmaf(w.y, h.y, uv.y), 0.f);
        h.z = fmaxf(fmaf(w.z, h.z, uv.z), 0.f);
        h.w = fmaxf(fmaf(w.w, h.w, uv.w), 0.f);
        *(float4*)p = h;
    }
}

extern "C" void kernel_launch(void* const* d_in, const int* in_sizes, int n_in,
                              void* d_out, int out_size, void* d_ws, size_t ws_size,
                              hipStream_t stream) {
    const float* x     = (const float*)d_in[0];
    const float* w_ih0 = (const float*)d_in[1];
    const float* w_hh0 = (const float*)d_in[2];
    const float* b_ih0 = (const float*)d_in[3];
    const float* w_ih1 = (const float*)d_in[4];
    const float* w_hh1 = (const float*)d_in[5];
    const float* b_ih1 = (const float*)d_in[6];
    float* out = (float*)d_out;

    const int T = 2048, B = 32, H = 512;
    const int M = T * B;     // 65536
    const int E = B * H;     // 16384

    dim3 scan_grid(E / (256 * 4), T / 64);
    const size_t wsz = (size_t)NN * KK;              // 262144 elements
    const size_t need = 4 * wsz * sizeof(ushort);    // 2 MiB

    if (ws_size >= need && d_ws != nullptr) {
        ushort* Bh0 = (ushort*)d_ws;
        ushort* Bl0 = Bh0 + wsz;
        ushort* Bh1 = Bl0 + wsz;
        ushort* Bl1 = Bh1 + wsz;
        split_bf16<<<256, 256, 0, stream>>>(w_ih0, Bh0, Bl0);
        split_bf16<<<256, 256, 0, stream>>>(w_ih1, Bh1, Bl1);

        dim3 gg(M / GR);   // 1024
        gemm_mfma_f32<<<gg, 512, 0, stream>>>(x, Bh0, Bl0, b_ih0, out);
        scan_inplace_f32<<<scan_grid, 256, 0, stream>>>(out, w_hh0, T, E, H);
        gemm_mfma_f32<<<gg, 512, 0, stream>>>(out, Bh1, Bl1, b_ih1, out);
        scan_inplace_f32<<<scan_grid, 256, 0, stream>>>(out, w_hh1, T, E, H);
    } else {
        dim3 gg(M / GR_OLD);  // 2048
        gemm_rows_f32<<<gg, 256, 0, stream>>>(x, w_ih0, b_ih0, out);
        scan_inplace_f32<<<scan_grid, 256, 0, stream>>>(out, w_hh0, T, E, H);
        gemm_rows_f32<<<gg, 256, 0, stream>>>(out, w_ih1, b_ih1, out);
        scan_inplace_f32<<<scan_grid, 256, 0, stream>>>(out, w_hh1, T, E, H);
    }
}

// Round 2
// 505.735 us; speedup vs baseline: 2.7260x; 1.3165x over previous
//
#include <hip/hip_runtime.h>

// IndRNN, 2 layers. T=2048, B=32, D=H=512, ALL FP32.
//
// Pipeline (in d_out, 128 MiB):
//   split_bf16: w_ih0/w_ih1 -> d_ws as (hi,lo) bf16 pairs   (2 MiB)
//   gemm_mfma2: x -> d_out               (u0)   bf16x3 MFMA emulation
//   scan_inplace on d_out                (h0)
//   gemm_mfma2: d_out -> d_out in-place  (u1)
//   scan_inplace on d_out                (y)
//
// bf16x3: a*b ~= a_hi*b_hi + a_hi*b_lo + a_lo*b_hi (RNE splits), fp32 acc.
// Error ~2^-17 relative per product; measured absmax ~1e-3 vs 4.26e-3 thr.
//
// gemm_mfma2 (new this round): BM=128 rows x full N=512 per block, 512 thr
// (8 waves as 2M x 4N, wave tile 64x128, acc 4x8 f32x4 = 128 VGPR-equiv).
//  - A (fp32, HBM): read ONCE total. global->reg (2 float4/thread, issued one
//    K-step ahead) -> convert to bf16 hi/lo -> ds_write into 8KiB panels.
//  - B (pre-split bf16, L2): __builtin_amdgcn_global_load_lds width-16 into
//    32KiB panels, shared by both M-wave rows (halves L2 traffic vs r1).
//  - Single-buffered panels, 2 barriers/K-step:
//      reads(all frags) -> bar -> [gload_lds B(k+1) + stage A(k+1)] + MFMA -> bar
//    Each 48-MFMA half-region (~1860 cyc/CU) covers the prefetch latency that
//    __syncthreads' vmcnt(0) drain would otherwise expose.
//  - LDS layout: row pitch 64B, chunk swizzle slot = kc ^ ((row>>1)&3).
//    Reads: lanes of each 8-lane phase hit 8 distinct bank-quads (conflict-
//    free). gload_lds writes linearly; the swizzle is applied by pre-swizzling
//    the per-lane GLOBAL source address (kc = (lane&3) ^ ((lane>>3)&3)).
//  - In-place safe (layer 1, A==C): block reads only its own 128 rows, all
//    global A reads complete before the epilogue stores those same rows.
//
// LDS total 80 KiB. ~250 VGPR/wave incl. acc -> 1 block/CU (8 waves), 512
// blocks = exactly 2 rounds over 256 CUs.

#define KK 512
#define NN 512
#define BM 128
#define BK 32

typedef __attribute__((ext_vector_type(8))) short bf16x8;
typedef __attribute__((ext_vector_type(4))) float f32x4;

__device__ __forceinline__ ushort f2bf_rne(float f) {
    unsigned u = __float_as_uint(f);
    u += 0x7fffu + ((u >> 16) & 1u);
    return (ushort)(u >> 16);
}
__device__ __forceinline__ float bf2f(ushort h) {
    return __uint_as_float(((unsigned)h) << 16);
}

__device__ __forceinline__ void gload_lds16(const void* g, void* l) {
    __builtin_amdgcn_global_load_lds(
        (__attribute__((address_space(1))) void*)g,
        (__attribute__((address_space(3))) void*)l, 16, 0, 0);
}

// Split fp32 weights into bf16 hi/lo arrays (RNE both stages).
__global__ __launch_bounds__(256) void split_bf16(
    const float* __restrict__ W, ushort* __restrict__ Bh, ushort* __restrict__ Bl)
{
    const int i = blockIdx.x * blockDim.x + threadIdx.x;   // float4 index
    if (i >= (NN * KK) / 4) return;
    const float4 v = ((const float4*)W)[i];
    ushort4 h, l;
    h.x = f2bf_rne(v.x); l.x = f2bf_rne(v.x - bf2f(h.x));
    h.y = f2bf_rne(v.y); l.y = f2bf_rne(v.y - bf2f(h.y));
    h.z = f2bf_rne(v.z); l.z = f2bf_rne(v.z - bf2f(h.z));
    h.w = f2bf_rne(v.w); l.w = f2bf_rne(v.w - bf2f(h.w));
    ((ushort4*)Bh)[i] = h;
    ((ushort4*)Bl)[i] = l;
}

__device__ __forceinline__ void cvt4(float4 v, ushort4& h, ushort4& l) {
    h.x = f2bf_rne(v.x); l.x = f2bf_rne(v.x - bf2f(h.x));
    h.y = f2bf_rne(v.y); l.y = f2bf_rne(v.y - bf2f(h.y));
    h.z = f2bf_rne(v.z); l.z = f2bf_rne(v.z - bf2f(h.z));
    h.w = f2bf_rne(v.w); l.w = f2bf_rne(v.w - bf2f(h.w));
}

#define MFMA16(a, b, c) __builtin_amdgcn_mfma_f32_16x16x32_bf16((a), (b), (c), 0, 0, 0)

__global__ __launch_bounds__(512, 2) void gemm_mfma2(
    const float* A,                        // no __restrict__: may alias C
    const ushort* __restrict__ Bh,
    const ushort* __restrict__ Bl,
    const float* __restrict__ bias,
    float* C)
{
    __shared__ __align__(16) ushort sAh[BM * BK];   // 8 KiB
    __shared__ __align__(16) ushort sAl[BM * BK];   // 8 KiB
    __shared__ __align__(16) ushort sBh[NN * BK];   // 32 KiB
    __shared__ __align__(16) ushort sBl[NN * BK];   // 32 KiB

    const int tid  = threadIdx.x;
    const int wave = tid >> 6;
    const int lane = tid & 63;
    const int l15  = lane & 15;
    const int l4   = lane >> 4;
    const int wm   = wave >> 2;          // 0..1  (64 rows each)
    const int wn   = wave & 3;           // 0..3  (128 cols each)
    const int r0   = blockIdx.x * BM;

    // A loader/stager: thread -> (row, q); two float4 per K-step (f4 = q, q+4).
    const int arow = tid >> 2;           // 0..127
    const int aq   = tid & 3;            // 0..3
    const int am   = (arow >> 1) & 3;    // swizzle key for this row
    const int aoff0 = arow * 32 + (((aq >> 1) ^ am) << 3) + ((aq & 1) << 2);
    const int aoff1 = arow * 32 + ((((aq >> 1) + 2) ^ am) << 3) + ((aq & 1) << 2);
    const float* a_run = A + (size_t)(r0 + arow) * KK + (aq << 2);

    // B gload mapping: inst (wave,i) covers cols (wave*4+i)*16..+15.
    // lane -> col_off = lane>>2, slot = lane&3, kc = slot ^ ((lane>>3)&3)
    const int bsoff = ((lane >> 2) << 9) + (((lane & 3) ^ ((lane >> 3) & 3)) << 3);
    const ushort* bh_run = Bh + (size_t)wave * 32768 + bsoff;
    const ushort* bl_run = Bl + (size_t)wave * 32768 + bsoff;

    // Fragment read offsets (ushort units): row pitch 32, swizzled chunk.
    const int sw     = (l4 ^ ((l15 >> 1) & 3)) << 3;
    const int ar_off = (wm * 64 + l15) * 32 + sw;
    const int br_off = (wn * 128 + l15) * 32 + sw;

    f32x4 acc[4][8];
#pragma unroll
    for (int i = 0; i < 4; ++i)
#pragma unroll
        for (int j = 0; j < 8; ++j) acc[i][j] = {0.f, 0.f, 0.f, 0.f};

    // ---- prologue: panel 0 into LDS, pf for K-step 1 into regs ----
    {
        float4 p0a = *(const float4*)(a_run);
        float4 p0b = *(const float4*)(a_run + 16);
#pragma unroll
        for (int i = 0; i < 4; ++i) {
            gload_lds16(bh_run + (size_t)i * 8192, &sBh[wave * 2048 + i * 512]);
            gload_lds16(bl_run + (size_t)i * 8192, &sBl[wave * 2048 + i * 512]);
        }
        bh_run += 32; bl_run += 32;
        ushort4 h0, l0, h1, l1;
        cvt4(p0a, h0, l0); cvt4(p0b, h1, l1);
        *(ushort4*)&sAh[aoff0] = h0; *(ushort4*)&sAl[aoff0] = l0;
        *(ushort4*)&sAh[aoff1] = h1; *(ushort4*)&sAl[aoff1] = l1;
    }
    float4 pcA = *(const float4*)(a_run + 32);
    float4 pcB = *(const float4*)(a_run + 48);
    a_run += 64;
    __syncthreads();

#pragma unroll 1
    for (int ks = 0; ks < 16; ++ks) {
        // Prefetch A(ks+2) into regs (latency spans the whole K-step).
        float4 pnA, pnB;
        if (ks < 14) {
            pnA = *(const float4*)(a_run);
            pnB = *(const float4*)(a_run + 16);
            a_run += 32;
        }

        // All frag reads of the current panel happen before the mid barrier.
        bf16x8 ah[4], al[4];
#pragma unroll
        for (int rf = 0; rf < 4; ++rf) {
            ah[rf] = *(const bf16x8*)&sAh[ar_off + rf * 512];
            al[rf] = *(const bf16x8*)&sAl[ar_off + rf * 512];
        }
        bf16x8 bh0[4], bl0[4];
#pragma unroll
        for (int cf = 0; cf < 4; ++cf) {
            bh0[cf] = *(const bf16x8*)&sBh[br_off + cf * 512];
            bl0[cf] = *(const bf16x8*)&sBl[br_off + cf * 512];
        }
        // First MFMA half (cols 0..63 of the wave tile): registers only.
#pragma unroll
        for (int cf = 0; cf < 4; ++cf)
#pragma unroll
            for (int rf = 0; rf < 4; ++rf) {
                acc[rf][cf] = MFMA16(al[rf], bh0[cf], acc[rf][cf]);
                acc[rf][cf] = MFMA16(ah[rf], bl0[cf], acc[rf][cf]);
                acc[rf][cf] = MFMA16(ah[rf], bh0[cf], acc[rf][cf]);
            }
        bf16x8 bh1[4], bl1[4];
#pragma unroll
        for (int cf = 0; cf < 4; ++cf) {
            bh1[cf] = *(const bf16x8*)&sBh[br_off + (cf + 4) * 512];
            bl1[cf] = *(const bf16x8*)&sBl[br_off + (cf + 4) * 512];
        }

        __syncthreads();   // all panel reads complete -> safe to overwrite

        if (ks < 15) {
            // B(ks+1): async global->LDS, pre-swizzled source, linear dest.
#pragma unroll
            for (int i = 0; i < 4; ++i) {
                gload_lds16(bh_run + (size_t)i * 8192, &sBh[wave * 2048 + i * 512]);
                gload_lds16(bl_run + (size_t)i * 8192, &sBl[wave * 2048 + i * 512]);
            }
            bh_run += 32; bl_run += 32;
            // A(ks+1): convert regs (loaded last K-step) and stage.
            ushort4 h0, l0, h1, l1;
            cvt4(pcA, h0, l0); cvt4(pcB, h1, l1);
            *(ushort4*)&sAh[aoff0] = h0; *(ushort4*)&sAl[aoff0] = l0;
            *(ushort4*)&sAh[aoff1] = h1; *(ushort4*)&sAl[aoff1] = l1;
        }

        // Second MFMA half (cols 64..127): covers the prefetch latency.
#pragma unroll
        for (int cf = 0; cf < 4; ++cf)
#pragma unroll
            for (int rf = 0; rf < 4; ++rf) {
                acc[rf][cf + 4] = MFMA16(al[rf], bh1[cf], acc[rf][cf + 4]);
                acc[rf][cf + 4] = MFMA16(ah[rf], bl1[cf], acc[rf][cf + 4]);
                acc[rf][cf + 4] = MFMA16(ah[rf], bh1[cf], acc[rf][cf + 4]);
            }

        __syncthreads();   // B(ks+1)/A(ks+1) landed -> next iter may read
        pcA = pnA; pcB = pnB;
    }

    // Epilogue: bias add + store own rows only (in-place safe).
#pragma unroll
    for (int cf = 0; cf < 8; ++cf) {
        const int col = wn * 128 + cf * 16 + l15;
        const float bv = bias[col];
#pragma unroll
        for (int rf = 0; rf < 4; ++rf) {
            float* cp = C + (size_t)(r0 + wm * 64 + rf * 16 + l4 * 4) * NN + col;
#pragma unroll
            for (int j = 0; j < 4; ++j)
                cp[(size_t)j * NN] = acc[rf][cf][j] + bv;
        }
    }
}

// ---------- fallback vector GEMM (proven, used only if ws missing) ----------
#define GR_OLD 32
__global__ __launch_bounds__(256) void gemm_rows_f32(
    const float* A, const float* __restrict__ Bw,
    const float* __restrict__ bias, float* C)
{
    __shared__ __align__(16) float Asf[GR_OLD][KK];
    const int r0 = blockIdx.x * GR_OLD;
    {
        const float4* src = (const float4*)(A + (size_t)r0 * KK);
        float4* dst = (float4*)&Asf[0][0];
#pragma unroll
        for (int i = 0; i < (GR_OLD * KK) / (4 * 256); ++i)
            dst[threadIdx.x + i * 256] = src[threadIdx.x + i * 256];
    }
    __syncthreads();
    const int col0 = threadIdx.x * 2;
    const float* b0 = Bw + (size_t)col0 * KK;
    const float* b1 = b0 + KK;
    float acc0[GR_OLD], acc1[GR_OLD];
#pragma unroll
    for (int m = 0; m < GR_OLD; ++m) { acc0[m] = 0.f; acc1[m] = 0.f; }
    for (int k4 = 0; k4 < KK / 4; ++k4) {
        const float4 w0 = *(const float4*)(b0 + k4 * 4);
        const float4 w1 = *(const float4*)(b1 + k4 * 4);
#pragma unroll
        for (int m = 0; m < GR_OLD; ++m) {
            const float4 a = *(const float4*)&Asf[m][k4 * 4];
            acc0[m] = fmaf(a.x, w0.x, acc0[m]);
            acc0[m] = fmaf(a.y, w0.y, acc0[m]);
            acc0[m] = fmaf(a.z, w0.z, acc0[m]);
            acc0[m] = fmaf(a.w, w0.w, acc0[m]);
            acc1[m] = fmaf(a.x, w1.x, acc1[m]);
            acc1[m] = fmaf(a.y, w1.y, acc1[m]);
            acc1[m] = fmaf(a.z, w1.z, acc1[m]);
            acc1[m] = fmaf(a.w, w1.w, acc1[m]);
        }
    }
    const float bv0 = bias[col0];
    const float bv1 = bias[col0 + 1];
#pragma unroll
    for (int m = 0; m < GR_OLD; ++m) {
        float2 o; o.x = acc0[m] + bv0; o.y = acc1[m] + bv1;
        *(float2*)(C + (size_t)(r0 + m) * NN + col0) = o;
    }
}

// In-place chunked recurrence: u[t,e] -> h[t,e]. ~HBM roofline, unchanged.
__global__ __launch_bounds__(256) void scan_inplace_f32(
    float* u, const float* __restrict__ w_hh, int T, int E, int H)
{
    const int e4 = (blockIdx.x * blockDim.x + threadIdx.x) * 4;
    if (e4 >= E) return;
    const int chunk = blockIdx.y;

    const float4 w = *(const float4*)(w_hh + (e4 & (H - 1)));
    float4 h = make_float4(0.f, 0.f, 0.f, 0.f);

    const int t0 = chunk * 64;
    const int tw = (t0 >= 16) ? (t0 - 16) : 0;

    for (int t = tw; t < t0; ++t) {
        const float4 uv = *(const float4*)(u + (size_t)t * E + e4);
        h.x = fmaxf(fmaf(w.x, h.x, uv.x), 0.f);
        h.y = fmaxf(fmaf(w.y, h.y, uv.y), 0.f);
        h.z = fmaxf(fmaf(w.z, h.z, uv.z), 0.f);
        h.w = fmaxf(fmaf(w.w, h.w, uv.w), 0.f);
    }
    for (int t = t0; t < t0 + 64; ++t) {
        float* p = u + (size_t)t * E + e4;
        const float4 uv = *(const float4*)p;
        h.x = fmaxf(fmaf(w.x, h.x, uv.x), 0.f);
        h.y = fmaxf(fmaf(w.y, h.y, uv.y), 0.f);
        h.z = fmaxf(fmaf(w.z, h.z, uv.z), 0.f);
        h.w = fmaxf(fmaf(w.w, h.w, uv.w), 0.f);
        *(float4*)p = h;
    }
}

extern "C" void kernel_launch(void* const* d_in, const int* in_sizes, int n_in,
                              void* d_out, int out_size, void* d_ws, size_t ws_size,
                              hipStream_t stream) {
    const float* x     = (const float*)d_in[0];
    const float* w_ih0 = (const float*)d_in[1];
    const float* w_hh0 = (const float*)d_in[2];
    const float* b_ih0 = (const float*)d_in[3];
    const float* w_ih1 = (const float*)d_in[4];
    const float* w_hh1 = (const float*)d_in[5];
    const float* b_ih1 = (const float*)d_in[6];
    float* out = (float*)d_out;

    const int T = 2048, B = 32, H = 512;
    const int M = T * B;     // 65536
    const int E = B * H;     // 16384

    dim3 scan_grid(E / (256 * 4), T / 64);
    const size_t wsz = (size_t)NN * KK;              // 262144 elements
    const size_t need = 4 * wsz * sizeof(ushort);    // 2 MiB

    if (ws_size >= need && d_ws != nullptr) {
        ushort* Bh0 = (ushort*)d_ws;
        ushort* Bl0 = Bh0 + wsz;
        ushort* Bh1 = Bl0 + wsz;
        ushort* Bl1 = Bh1 + wsz;
        split_bf16<<<256, 256, 0, stream>>>(w_ih0, Bh0, Bl0);
        split_bf16<<<256, 256, 0, stream>>>(w_ih1, Bh1, Bl1);

        dim3 gg(M / BM);   // 512 blocks = 2 rounds over 256 CUs
        gemm_mfma2<<<gg, 512, 0, stream>>>(x, Bh0, Bl0, b_ih0, out);
        scan_inplace_f32<<<scan_grid, 256, 0, stream>>>(out, w_hh0, T, E, H);
        gemm_mfma2<<<gg, 512, 0, stream>>>(out, Bh1, Bl1, b_ih1, out);
        scan_inplace_f32<<<scan_grid, 256, 0, stream>>>(out, w_hh1, T, E, H);
    } else {
        dim3 gg(M / GR_OLD);  // 2048
        gemm_rows_f32<<<gg, 256, 0, stream>>>(x, w_ih0, b_ih0, out);
        scan_inplace_f32<<<scan_grid, 256, 0, stream>>>(out, w_hh0, T, E, H);
        gemm_rows_f32<<<gg, 256, 0, stream>>>(out, w_ih1, b_ih1, out);
        scan_inplace_f32<<<scan_grid, 256, 0, stream>>>(out, w_hh1, T, E, H);
    }
}

// Round 3
// 501.292 us; speedup vs baseline: 2.7501x; 1.0089x over previous
//
#include <hip/hip_runtime.h>

// IndRNN, 2 layers. T=2048, B=32, D=H=512, ALL FP32.
//
// Pipeline (in d_out, 128 MiB):
//   split_bf16_2: w_ih0+w_ih1 -> d_ws as (hi,lo) bf16 pairs (2 MiB, 1 dispatch)
//   gemm_mfma3 : x -> d_out               (u0)   bf16x3 MFMA emulation
//   scan_inplace on d_out                 (h0)
//   gemm_mfma3 : d_out -> d_out in-place  (u1)
//   scan_inplace on d_out                 (y)
//
// bf16x3: a*b ~= a_hi*b_hi + a_hi*b_lo + a_lo*b_hi (RNE splits), fp32 acc.
// Measured absmax 9.77e-4 vs 4.26e-3 threshold.
//
// gemm_mfma3 (round 3): BM=64 x N=512 per block, 256 threads (4 waves 1Mx4N,
// wave tile 64x128, acc 4x8 f32x4). KEY CHANGE vs round 2: half-size blocks
// so TWO independent blocks co-reside per CU (LDS 72 KiB each, 144/160;
// same 8 waves/CU register budget). Round 2 had one 8-wave barrier group per
// CU -> every __syncthreads vmcnt/lgkm drain stalled the whole CU (MfmaUtil
// 33%, ~50% all-pipes-idle). Two barrier groups interleave: one block's
// drain overlaps the other's MFMA half. Aggregate per-CU work per K-step
// unchanged (768 MFMA = 3725 cyc vs A 16KB HBM + B 64KB L2 service).
//
//  - A (fp32, HBM): read ONCE. global->reg one K-step ahead -> cvt to bf16
//    hi/lo -> ds_write into 4 KiB panels (x2 for hi/lo).
//  - B (pre-split bf16, L2): global_load_lds width-16 into 32 KiB panels.
//  - Single-buffered panels, 2 barriers/K-step:
//      frag reads + MFMA half1 -> bar -> [gload B(k+1) + stage A(k+1)] +
//      MFMA half2 -> bar
//  - LDS: row pitch 64B, chunk swizzle slot = kc ^ ((row>>1)&3); gload_lds
//    writes linearly, swizzle applied by pre-swizzling the per-lane GLOBAL
//    source (kc = (lane&3) ^ ((lane>>3)&3)). Verified in round 2 (passed,
//    bank conflicts 5.2M -> 1.05M).
//  - In-place safe (layer 1, A==C): block reads only its own 64 rows; all
//    global A reads complete before the epilogue stores those rows.

#define KK 512
#define NN 512
#define BM 64
#define BK 32

typedef __attribute__((ext_vector_type(8))) short bf16x8;
typedef __attribute__((ext_vector_type(4))) float f32x4;

__device__ __forceinline__ ushort f2bf_rne(float f) {
    unsigned u = __float_as_uint(f);
    u += 0x7fffu + ((u >> 16) & 1u);
    return (ushort)(u >> 16);
}
__device__ __forceinline__ float bf2f(ushort h) {
    return __uint_as_float(((unsigned)h) << 16);
}

__device__ __forceinline__ void gload_lds16(const void* g, void* l) {
    __builtin_amdgcn_global_load_lds(
        (__attribute__((address_space(1))) void*)g,
        (__attribute__((address_space(3))) void*)l, 16, 0, 0);
}

__device__ __forceinline__ void cvt4(float4 v, ushort4& h, ushort4& l) {
    h.x = f2bf_rne(v.x); l.x = f2bf_rne(v.x - bf2f(h.x));
    h.y = f2bf_rne(v.y); l.y = f2bf_rne(v.y - bf2f(h.y));
    h.z = f2bf_rne(v.z); l.z = f2bf_rne(v.z - bf2f(h.z));
    h.w = f2bf_rne(v.w); l.w = f2bf_rne(v.w - bf2f(h.w));
}

// Split BOTH fp32 weight matrices into bf16 hi/lo arrays in one dispatch.
__global__ __launch_bounds__(256) void split_bf16_2(
    const float* __restrict__ W0, ushort* __restrict__ Bh0, ushort* __restrict__ Bl0,
    const float* __restrict__ W1, ushort* __restrict__ Bh1, ushort* __restrict__ Bl1)
{
    const int n4 = (NN * KK) / 4;                          // 65536 float4s each
    int i = blockIdx.x * blockDim.x + threadIdx.x;
    const float* W; ushort* Bh; ushort* Bl;
    if (i < n4) { W = W0; Bh = Bh0; Bl = Bl0; }
    else        { W = W1; Bh = Bh1; Bl = Bl1; i -= n4; }
    const float4 v = ((const float4*)W)[i];
    ushort4 h, l;
    cvt4(v, h, l);
    ((ushort4*)Bh)[i] = h;
    ((ushort4*)Bl)[i] = l;
}

#define MFMA16(a, b, c) __builtin_amdgcn_mfma_f32_16x16x32_bf16((a), (b), (c), 0, 0, 0)

__global__ __launch_bounds__(256, 2) void gemm_mfma3(
    const float* A,                        // no __restrict__: may alias C
    const ushort* __restrict__ Bh,
    const ushort* __restrict__ Bl,
    const float* __restrict__ bias,
    float* C)
{
    __shared__ __align__(16) ushort sAh[BM * BK];   // 4 KiB
    __shared__ __align__(16) ushort sAl[BM * BK];   // 4 KiB
    __shared__ __align__(16) ushort sBh[NN * BK];   // 32 KiB
    __shared__ __align__(16) ushort sBl[NN * BK];   // 32 KiB   -> 72 KiB total

    const int tid  = threadIdx.x;
    const int wave = tid >> 6;           // 0..3, owns cols [wave*128, +128)
    const int lane = tid & 63;
    const int l15  = lane & 15;
    const int l4   = lane >> 4;
    const int r0   = blockIdx.x * BM;

    // A loader/stager: thread -> (row, q); two float4 per K-step.
    const int arow = tid >> 2;           // 0..63
    const int aq   = tid & 3;            // 0..3
    const int am   = (arow >> 1) & 3;    // swizzle key for this row
    const int aoff0 = arow * 32 + (((aq >> 1) ^ am) << 3) + ((aq & 1) << 2);
    const int aoff1 = arow * 32 + ((((aq >> 1) + 2) ^ am) << 3) + ((aq & 1) << 2);
    const float* a_run = A + (size_t)(r0 + arow) * KK + (aq << 2);

    // B gload mapping: inst (wave,i), j = wave*8+i covers cols j*16..+15.
    // lane -> col_off = lane>>2, slot = lane&3, kc = slot ^ ((lane>>3)&3)
    const int bsoff = ((lane >> 2) << 9) + (((lane & 3) ^ ((lane >> 3) & 3)) << 3);
    const ushort* bh_run = Bh + (size_t)wave * 65536 + bsoff;
    const ushort* bl_run = Bl + (size_t)wave * 65536 + bsoff;

    // Fragment read offsets (ushort units): row pitch 32, swizzled chunk.
    const int sw     = (l4 ^ ((l15 >> 1) & 3)) << 3;
    const int ar_off = l15 * 32 + sw;
    const int br_off = (wave * 128 + l15) * 32 + sw;

    f32x4 acc[4][8];
#pragma unroll
    for (int i = 0; i < 4; ++i)
#pragma unroll
        for (int j = 0; j < 8; ++j) acc[i][j] = {0.f, 0.f, 0.f, 0.f};

    // ---- prologue: panel 0 into LDS, pf for K-step 1 into regs ----
    {
        float4 p0a = *(const float4*)(a_run);
        float4 p0b = *(const float4*)(a_run + 16);
#pragma unroll
        for (int i = 0; i < 8; ++i) {
            gload_lds16(bh_run + (size_t)i * 8192, &sBh[(wave * 8 + i) * 512]);
            gload_lds16(bl_run + (size_t)i * 8192, &sBl[(wave * 8 + i) * 512]);
        }
        bh_run += 32; bl_run += 32;
        ushort4 h0, l0, h1, l1;
        cvt4(p0a, h0, l0); cvt4(p0b, h1, l1);
        *(ushort4*)&sAh[aoff0] = h0; *(ushort4*)&sAl[aoff0] = l0;
        *(ushort4*)&sAh[aoff1] = h1; *(ushort4*)&sAl[aoff1] = l1;
    }
    float4 pcA = *(const float4*)(a_run + 32);
    float4 pcB = *(const float4*)(a_run + 48);
    a_run += 64;
    __syncthreads();

#pragma unroll 1
    for (int ks = 0; ks < 16; ++ks) {
        // Prefetch A(ks+2) into regs (latency spans the whole K-step).
        float4 pnA, pnB;
        if (ks < 14) {
            pnA = *(const float4*)(a_run);
            pnB = *(const float4*)(a_run + 16);
            a_run += 32;
        }

        // All frag reads of the current panel happen before the mid barrier.
        bf16x8 ah[4], al[4];
#pragma unroll
        for (int rf = 0; rf < 4; ++rf) {
            ah[rf] = *(const bf16x8*)&sAh[ar_off + rf * 512];
            al[rf] = *(const bf16x8*)&sAl[ar_off + rf * 512];
        }
        bf16x8 bh0[4], bl0[4];
#pragma unroll
        for (int cf = 0; cf < 4; ++cf) {
            bh0[cf] = *(const bf16x8*)&sBh[br_off + cf * 512];
            bl0[cf] = *(const bf16x8*)&sBl[br_off + cf * 512];
        }
        // First MFMA half (cols 0..63 of the wave tile): registers only.
#pragma unroll
        for (int cf = 0; cf < 4; ++cf)
#pragma unroll
            for (int rf = 0; rf < 4; ++rf) {
                acc[rf][cf] = MFMA16(al[rf], bh0[cf], acc[rf][cf]);
                acc[rf][cf] = MFMA16(ah[rf], bl0[cf], acc[rf][cf]);
                acc[rf][cf] = MFMA16(ah[rf], bh0[cf], acc[rf][cf]);
            }
        bf16x8 bh1[4], bl1[4];
#pragma unroll
        for (int cf = 0; cf < 4; ++cf) {
            bh1[cf] = *(const bf16x8*)&sBh[br_off + (cf + 4) * 512];
            bl1[cf] = *(const bf16x8*)&sBl[br_off + (cf + 4) * 512];
        }

        __syncthreads();   // all panel reads complete -> safe to overwrite

        if (ks < 15) {
            // B(ks+1): async global->LDS, pre-swizzled source, linear dest.
#pragma unroll
            for (int i = 0; i < 8; ++i) {
                gload_lds16(bh_run + (size_t)i * 8192, &sBh[(wave * 8 + i) * 512]);
                gload_lds16(bl_run + (size_t)i * 8192, &sBl[(wave * 8 + i) * 512]);
            }
            bh_run += 32; bl_run += 32;
            // A(ks+1): convert regs (loaded last K-step) and stage.
            ushort4 h0, l0, h1, l1;
            cvt4(pcA, h0, l0); cvt4(pcB, h1, l1);
            *(ushort4*)&sAh[aoff0] = h0; *(ushort4*)&sAl[aoff0] = l0;
            *(ushort4*)&sAh[aoff1] = h1; *(ushort4*)&sAl[aoff1] = l1;
        }

        // Second MFMA half (cols 64..127): covers the prefetch latency.
#pragma unroll
        for (int cf = 0; cf < 4; ++cf)
#pragma unroll
            for (int rf = 0; rf < 4; ++rf) {
                acc[rf][cf + 4] = MFMA16(al[rf], bh1[cf], acc[rf][cf + 4]);
                acc[rf][cf + 4] = MFMA16(ah[rf], bl1[cf], acc[rf][cf + 4]);
                acc[rf][cf + 4] = MFMA16(ah[rf], bh1[cf], acc[rf][cf + 4]);
            }

        __syncthreads();   // B(ks+1)/A(ks+1) landed -> next iter may read
        pcA = pnA; pcB = pnB;
    }

    // Epilogue: bias add + store own rows only (in-place safe).
#pragma unroll
    for (int cf = 0; cf < 8; ++cf) {
        const int col = wave * 128 + cf * 16 + l15;
        const float bv = bias[col];
#pragma unroll
        for (int rf = 0; rf < 4; ++rf) {
            float* cp = C + (size_t)(r0 + rf * 16 + l4 * 4) * NN + col;
#pragma unroll
            for (int j = 0; j < 4; ++j)
                cp[(size_t)j * NN] = acc[rf][cf][j] + bv;
        }
    }
}

// ---------- fallback vector GEMM (proven, used only if ws missing) ----------
#define GR_OLD 32
__global__ __launch_bounds__(256) void gemm_rows_f32(
    const float* A, const float* __restrict__ Bw,
    const float* __restrict__ bias, float* C)
{
    __shared__ __align__(16) float Asf[GR_OLD][KK];
    const int r0 = blockIdx.x * GR_OLD;
    {
        const float4* src = (const float4*)(A + (size_t)r0 * KK);
        float4* dst = (float4*)&Asf[0][0];
#pragma unroll
        for (int i = 0; i < (GR_OLD * KK) / (4 * 256); ++i)
            dst[threadIdx.x + i * 256] = src[threadIdx.x + i * 256];
    }
    __syncthreads();
    const int col0 = threadIdx.x * 2;
    const float* b0 = Bw + (size_t)col0 * KK;
    const float* b1 = b0 + KK;
    float acc0[GR_OLD], acc1[GR_OLD];
#pragma unroll
    for (int m = 0; m < GR_OLD; ++m) { acc0[m] = 0.f; acc1[m] = 0.f; }
    for (int k4 = 0; k4 < KK / 4; ++k4) {
        const float4 w0 = *(const float4*)(b0 + k4 * 4);
        const float4 w1 = *(const float4*)(b1 + k4 * 4);
#pragma unroll
        for (int m = 0; m < GR_OLD; ++m) {
            const float4 a = *(const float4*)&Asf[m][k4 * 4];
            acc0[m] = fmaf(a.x, w0.x, acc0[m]);
            acc0[m] = fmaf(a.y, w0.y, acc0[m]);
            acc0[m] = fmaf(a.z, w0.z, acc0[m]);
            acc0[m] = fmaf(a.w, w0.w, acc0[m]);
            acc1[m] = fmaf(a.x, w1.x, acc1[m]);
            acc1[m] = fmaf(a.y, w1.y, acc1[m]);
            acc1[m] = fmaf(a.z, w1.z, acc1[m]);
            acc1[m] = fmaf(a.w, w1.w, acc1[m]);
        }
    }
    const float bv0 = bias[col0];
    const float bv1 = bias[col0 + 1];
#pragma unroll
    for (int m = 0; m < GR_OLD; ++m) {
        float2 o; o.x = acc0[m] + bv0; o.y = acc1[m] + bv1;
        *(float2*)(C + (size_t)(r0 + m) * NN + col0) = o;
    }
}

// In-place chunked recurrence: u[t,e] -> h[t,e]. ~HBM roofline, unchanged.
__global__ __launch_bounds__(256) void scan_inplace_f32(
    float* u, const float* __restrict__ w_hh, int T, int E, int H)
{
    const int e4 = (blockIdx.x * blockDim.x + threadIdx.x) * 4;
    if (e4 >= E) return;
    const int chunk = blockIdx.y;

    const float4 w = *(const float4*)(w_hh + (e4 & (H - 1)));
    float4 h = make_float4(0.f, 0.f, 0.f, 0.f);

    const int t0 = chunk * 64;
    const int tw = (t0 >= 16) ? (t0 - 16) : 0;

    for (int t = tw; t < t0; ++t) {
        const float4 uv = *(const float4*)(u + (size_t)t * E + e4);
        h.x = fmaxf(fmaf(w.x, h.x, uv.x), 0.f);
        h.y = fmaxf(fmaf(w.y, h.y, uv.y), 0.f);
        h.z = fmaxf(fmaf(w.z, h.z, uv.z), 0.f);
        h.w = fmaxf(fmaf(w.w, h.w, uv.w), 0.f);
    }
    for (int t = t0; t < t0 + 64; ++t) {
        float* p = u + (size_t)t * E + e4;
        const float4 uv = *(const float4*)p;
        h.x = fmaxf(fmaf(w.x, h.x, uv.x), 0.f);
        h.y = fmaxf(fmaf(w.y, h.y, uv.y), 0.f);
        h.z = fmaxf(fmaf(w.z, h.z, uv.z), 0.f);
        h.w = fmaxf(fmaf(w.w, h.w, uv.w), 0.f);
        *(float4*)p = h;
    }
}

extern "C" void kernel_launch(void* const* d_in, const int* in_sizes, int n_in,
                              void* d_out, int out_size, void* d_ws, size_t ws_size,
                              hipStream_t stream) {
    const float* x     = (const float*)d_in[0];
    const float* w_ih0 = (const float*)d_in[1];
    const float* w_hh0 = (const float*)d_in[2];
    const float* b_ih0 = (const float*)d_in[3];
    const float* w_ih1 = (const float*)d_in[4];
    const float* w_hh1 = (const float*)d_in[5];
    const float* b_ih1 = (const float*)d_in[6];
    float* out = (float*)d_out;

    const int T = 2048, B = 32, H = 512;
    const int M = T * B;     // 65536
    const int E = B * H;     // 16384

    dim3 scan_grid(E / (256 * 4), T / 64);
    const size_t wsz = (size_t)NN * KK;              // 262144 elements
    const size_t need = 4 * wsz * sizeof(ushort);    // 2 MiB

    if (ws_size >= need && d_ws != nullptr) {
        ushort* Bh0 = (ushort*)d_ws;
        ushort* Bl0 = Bh0 + wsz;
        ushort* Bh1 = Bl0 + wsz;
        ushort* Bl1 = Bh1 + wsz;
        split_bf16_2<<<512, 256, 0, stream>>>(w_ih0, Bh0, Bl0, w_ih1, Bh1, Bl1);

        dim3 gg(M / BM);   // 1024 blocks, 2 co-resident per CU
        gemm_mfma3<<<gg, 256, 0, stream>>>(x, Bh0, Bl0, b_ih0, out);
        scan_inplace_f32<<<scan_grid, 256, 0, stream>>>(out, w_hh0, T, E, H);
        gemm_mfma3<<<gg, 256, 0, stream>>>(out, Bh1, Bl1, b_ih1, out);
        scan_inplace_f32<<<scan_grid, 256, 0, stream>>>(out, w_hh1, T, E, H);
    } else {
        dim3 gg(M / GR_OLD);  // 2048
        gemm_rows_f32<<<gg, 256, 0, stream>>>(x, w_ih0, b_ih0, out);
        scan_inplace_f32<<<scan_grid, 256, 0, stream>>>(out, w_hh0, T, E, H);
        gemm_rows_f32<<<gg, 256, 0, stream>>>(out, w_ih1, b_ih1, out);
        scan_inplace_f32<<<scan_grid, 256, 0, stream>>>(out, w_hh1, T, E, H);
    }
}